// Round 1
// baseline (902.532 us; speedup 1.0000x reference)
//
#include <hip/hip_runtime.h>

// WinGNN: conv-encode -> radius-KNN -> 4-layer GNN. All fp32 (round 1 baseline).
//
// Workspace layout (bytes, all 1KB-aligned; total ~25.8 MB):
//   wT    @ 0        : 147x64 transposed conv filters (40960 B slot)
//   enc   @ 40960    : 2048x64   (524288 B)
//   hA    @ 565248   : 2048x512  (4 MB)   node embeddings (ping/pong in place)
//   agg   @ 4759552  : 2048x512  (4 MB)
//   part  @ 8953856  : 4x2048x512 (16 MB) split-K partials
//   nbr   @ 25731072 : 2048x5 int (40960 B slot)
//   den   @ 25772032 : 2048 float

#define NNODES 2048

// ---------- transpose conv_w [64][147] -> wT [147][64] ----------
__global__ __launch_bounds__(256) void transpose_w_kernel(
    const float* __restrict__ w, float* __restrict__ wT) {
  int i = blockIdx.x * 256 + threadIdx.x;
  if (i < 64 * 147) {
    int c = i / 147, k = i % 147;
    wT[k * 64 + c] = w[i];
  }
}

// ---------- conv7x7 s2 SAME + bias + relu + global avg pool ----------
// one block per image; 256 threads; thread = 2x2 output pixels x 8 channels/group
__global__ __launch_bounds__(256) void conv_pool_kernel(
    const float* __restrict__ imgs, const float* __restrict__ wT,
    const float* __restrict__ cb, float* __restrict__ enc) {
  __shared__ float s_img[3][69][72];   // padded: idx = [ic][iy+2][ix+2], zeros at halo
  __shared__ float s_pool[64];
  const int n = blockIdx.x;
  const int tid = threadIdx.x;

  float* sf = &s_img[0][0][0];
  for (int i = tid; i < 3 * 69 * 72; i += 256) sf[i] = 0.f;
  if (tid < 64) s_pool[tid] = 0.f;
  __syncthreads();  // zeros complete before interior overwrite (different writers)

  const float4* src = (const float4*)(imgs + (size_t)n * 12288);
  for (int i = tid; i < 3072; i += 256) {
    float4 v = src[i];
    int e = i << 2;
    int c = e >> 12;
    int rem = e & 4095;
    int y = rem >> 6, x = rem & 63;
    float* dst = &s_img[c][y + 2][x + 2];
    dst[0] = v.x; dst[1] = v.y; dst[2] = v.z; dst[3] = v.w;
  }
  __syncthreads();

  const int tx = tid & 15;   // ox0 = 2*tx (handles ox0, ox0+1)
  const int ty = tid >> 4;   // oy = ty and ty+16
  const int col0 = tx << 2;  // LDS col of ix+2 for (ox0, kx=0)

  for (int cg = 0; cg < 8; ++cg) {
    float acc0[8] = {}, acc1[8] = {}, acc2[8] = {}, acc3[8] = {};
    for (int ic = 0; ic < 3; ++ic) {
      for (int ky = 0; ky < 7; ++ky) {
        const float* row0 = &s_img[ic][2 * ty + ky][col0];
        const float* row1 = &s_img[ic][2 * ty + 32 + ky][col0];
        float in0[9], in1[9];
        float4 a0 = *(const float4*)(row0);
        float4 a1 = *(const float4*)(row0 + 4);
        float4 b0 = *(const float4*)(row1);
        float4 b1 = *(const float4*)(row1 + 4);
        in0[0]=a0.x; in0[1]=a0.y; in0[2]=a0.z; in0[3]=a0.w;
        in0[4]=a1.x; in0[5]=a1.y; in0[6]=a1.z; in0[7]=a1.w;
        in0[8]=row0[8];
        in1[0]=b0.x; in1[1]=b0.y; in1[2]=b0.z; in1[3]=b0.w;
        in1[4]=b1.x; in1[5]=b1.y; in1[6]=b1.z; in1[7]=b1.w;
        in1[8]=row1[8];
        const float* wp = wT + (ic * 49 + ky * 7) * 64 + (cg << 3);
#pragma unroll
        for (int kx = 0; kx < 7; ++kx) {
#pragma unroll
          for (int cc = 0; cc < 8; ++cc) {
            float w = wp[kx * 64 + cc];   // wave-uniform -> scalar load
            acc0[cc] = fmaf(in0[kx],     w, acc0[cc]);
            acc1[cc] = fmaf(in0[kx + 2], w, acc1[cc]);
            acc2[cc] = fmaf(in1[kx],     w, acc2[cc]);
            acc3[cc] = fmaf(in1[kx + 2], w, acc3[cc]);
          }
        }
      }
    }
#pragma unroll
    for (int cc = 0; cc < 8; ++cc) {
      float b = cb[(cg << 3) + cc];
      float p = fmaxf(acc0[cc] + b, 0.f) + fmaxf(acc1[cc] + b, 0.f)
              + fmaxf(acc2[cc] + b, 0.f) + fmaxf(acc3[cc] + b, 0.f);
#pragma unroll
      for (int off = 32; off > 0; off >>= 1) p += __shfl_xor(p, off);
      if ((tid & 63) == 0) atomicAdd(&s_pool[(cg << 3) + cc], p);
    }
  }
  __syncthreads();
  if (tid < 64) enc[n * 64 + tid] = s_pool[tid] * (1.f / 1024.f);
}

// ---------- proj: relu(enc[2048,64] @ pw[64,512] + pb) -> h[2048,512] ----------
__global__ __launch_bounds__(256) void proj_kernel(
    const float* __restrict__ enc, const float* __restrict__ pw,
    const float* __restrict__ pb, float* __restrict__ h) {
  int c = ((blockIdx.x & 1) << 8) | threadIdx.x;
  int r0 = (blockIdx.x >> 1) << 3;
  float bias = pb[c];
  float acc[8];
#pragma unroll
  for (int r = 0; r < 8; ++r) acc[r] = bias;
#pragma unroll 4
  for (int k = 0; k < 64; ++k) {
    float w = pw[k * 512 + c];
#pragma unroll
    for (int r = 0; r < 8; ++r) acc[r] = fmaf(enc[(r0 + r) * 64 + k], w, acc[r]);
  }
#pragma unroll
  for (int r = 0; r < 8; ++r) h[(r0 + r) * 512 + c] = fmaxf(acc[r], 0.f);
}

// ---------- radius-KNN: top-5 nearest within r2<=2, no self ----------
__global__ __launch_bounds__(256) void knn_kernel(
    const float* __restrict__ pos, int* __restrict__ nbr, float* __restrict__ den) {
  int i = blockIdx.x * 256 + threadIdx.x;
  float2 p = ((const float2*)pos)[i];
  float px = p.x * 32.f, py = p.y * 32.f;
  float bd[5] = {1e30f, 1e30f, 1e30f, 1e30f, 1e30f};
  int   bi[5] = {-1, -1, -1, -1, -1};
  for (int j = 0; j < NNODES; ++j) {
    float2 q = ((const float2*)pos)[j];   // wave-uniform -> scalar load
    float dx = q.x * 32.f - px, dy = q.y * 32.f - py;
    float d2 = dx * dx + dy * dy;
    if (d2 <= 2.0f && j != i && d2 < bd[4]) {
      float nd = d2; int ni = j;
#pragma unroll
      for (int k = 0; k < 5; ++k) {      // fully unrolled: static indices only
        bool s = nd < bd[k];
        float td = bd[k]; int ti = bi[k];
        bd[k] = s ? nd : td;  bi[k] = s ? ni : ti;
        nd = s ? td : nd;     ni = s ? ti : ni;
      }
    }
  }
  int cnt = 0;
#pragma unroll
  for (int k = 0; k < 5; ++k) cnt += (bi[k] >= 0);
#pragma unroll
  for (int k = 0; k < 5; ++k) nbr[i * 5 + k] = bi[k];
  den[i] = (float)(cnt > 0 ? cnt : 1);
}

// ---------- agg[i][d] = sum_valid h[nbr][d] / den[i] ----------
__global__ __launch_bounds__(256) void agg_kernel(
    const float* __restrict__ h, const int* __restrict__ nbr,
    const float* __restrict__ den, float* __restrict__ agg) {
  int i = blockIdx.x >> 1;
  int d = ((blockIdx.x & 1) << 8) + threadIdx.x;
  float s = 0.f;
#pragma unroll
  for (int k = 0; k < 5; ++k) {
    int j = nbr[i * 5 + k];               // wave-uniform
    if (j >= 0) s += h[j * 512 + d];      // coalesced
  }
  agg[i * 512 + d] = s / den[i];
}

// ---------- GNN GEMM: part[split] += h@Ws + agg@Wn (128x128 tile, 8x8 micro, splitK=4) ----------
__global__ __launch_bounds__(256) void gnn_gemm_kernel(
    const float* __restrict__ hmat, const float* __restrict__ agg,
    const float* __restrict__ wself, const float* __restrict__ wnbr,
    float* __restrict__ part) {
  __shared__ float s_a[16][132];   // A-tile transposed [k][r], padded
  __shared__ float s_b[16][128];
  int bid = blockIdx.x;
  int split = bid & 3;
  int bn = (bid >> 2) & 3;
  int bm = bid >> 4;
  int r0 = bm << 7, c0 = bn << 7, k0 = split << 7;
  int tid = threadIdx.x;
  int ty = tid >> 4, tx = tid & 15;
  float acc[8][8] = {};

  int ar = tid >> 1, ak = (tid & 1) << 3;     // A load: 128 rows x 16 k
  int bk = tid >> 5, bc = (tid & 31) << 2;    // B load: 16 k x 128 cols

  for (int phase = 0; phase < 2; ++phase) {
    const float* A = phase ? agg : hmat;
    const float* W = phase ? wnbr : wself;
    for (int kt = 0; kt < 128; kt += 16) {
      int kb = k0 + kt;
      float4 v0 = *(const float4*)&A[(r0 + ar) * 512 + kb + ak];
      float4 v1 = *(const float4*)&A[(r0 + ar) * 512 + kb + ak + 4];
      float4 w0 = *(const float4*)&W[(kb + bk) * 512 + c0 + bc];
      float4 w1 = *(const float4*)&W[(kb + bk + 8) * 512 + c0 + bc];
      __syncthreads();  // previous compute done before LDS overwrite
      s_a[ak + 0][ar] = v0.x; s_a[ak + 1][ar] = v0.y;
      s_a[ak + 2][ar] = v0.z; s_a[ak + 3][ar] = v0.w;
      s_a[ak + 4][ar] = v1.x; s_a[ak + 5][ar] = v1.y;
      s_a[ak + 6][ar] = v1.z; s_a[ak + 7][ar] = v1.w;
      *(float4*)&s_b[bk][bc] = w0;
      *(float4*)&s_b[bk + 8][bc] = w1;
      __syncthreads();
#pragma unroll
      for (int kk = 0; kk < 16; ++kk) {
        float a[8], b[8];
        *(float4*)&a[0] = *(const float4*)&s_a[kk][ty << 3];
        *(float4*)&a[4] = *(const float4*)&s_a[kk][(ty << 3) + 4];
#pragma unroll
        for (int j = 0; j < 8; ++j) b[j] = s_b[kk][tx + (j << 4)];  // stride-16 cols: bank-clean
#pragma unroll
        for (int ii = 0; ii < 8; ++ii)
#pragma unroll
          for (int j = 0; j < 8; ++j)
            acc[ii][j] = fmaf(a[ii], b[j], acc[ii][j]);
      }
    }
  }
  __syncthreads();
  float* dst = part + (size_t)split * (NNODES * 512);
#pragma unroll
  for (int ii = 0; ii < 8; ++ii) {
    int r = r0 + (ty << 3) + ii;
#pragma unroll
    for (int j = 0; j < 8; ++j)
      dst[r * 512 + c0 + tx + (j << 4)] = acc[ii][j];
  }
}

// ---------- reduce splits + bias + relu ----------
__global__ __launch_bounds__(256) void gnn_reduce_kernel(
    const float* __restrict__ part, const float* __restrict__ bg,
    float* __restrict__ hout) {
  int i = blockIdx.x * 256 + threadIdx.x;   // float4 index, 262144 total
  const float4* p = (const float4*)part;
  float4 a = p[i];
  float4 b = p[i + 262144];
  float4 c = p[i + 524288];
  float4 d = p[i + 786432];
  float4 bb = ((const float4*)bg)[i & 127];
  float4 o;
  o.x = fmaxf(a.x + b.x + c.x + d.x + bb.x, 0.f);
  o.y = fmaxf(a.y + b.y + c.y + d.y + bb.y, 0.f);
  o.z = fmaxf(a.z + b.z + c.z + d.z + bb.z, 0.f);
  o.w = fmaxf(a.w + b.w + c.w + d.w + bb.w, 0.f);
  ((float4*)hout)[i] = o;
}

extern "C" void kernel_launch(void* const* d_in, const int* in_sizes, int n_in,
                              void* d_out, int out_size, void* d_ws, size_t ws_size,
                              hipStream_t stream) {
  const float* imgs   = (const float*)d_in[0];
  const float* pos    = (const float*)d_in[1];
  const float* conv_w = (const float*)d_in[2];
  const float* conv_b = (const float*)d_in[3];
  const float* proj_w = (const float*)d_in[4];
  const float* proj_b = (const float*)d_in[5];
  const float* w_self = (const float*)d_in[6];
  const float* w_nbr  = (const float*)d_in[7];
  const float* b_gnn  = (const float*)d_in[8];

  char* ws = (char*)d_ws;
  float* wT   = (float*)(ws);
  float* enc  = (float*)(ws + 40960);
  float* hA   = (float*)(ws + 40960 + 524288);
  float* agg  = (float*)(ws + 40960 + 524288 + 4194304);
  float* part = (float*)(ws + 40960 + 524288 + 2 * 4194304);
  int*   nbr  = (int*)  (ws + 40960 + 524288 + 2 * 4194304 + 16777216);
  float* den  = (float*)(ws + 40960 + 524288 + 2 * 4194304 + 16777216 + 40960);

  transpose_w_kernel<<<37, 256, 0, stream>>>(conv_w, wT);
  knn_kernel<<<8, 256, 0, stream>>>(pos, nbr, den);
  conv_pool_kernel<<<2048, 256, 0, stream>>>(imgs, wT, conv_b, enc);
  proj_kernel<<<512, 256, 0, stream>>>(enc, proj_w, proj_b, hA);

  for (int l = 0; l < 4; ++l) {
    const float* Wl = w_self + l * 262144;
    const float* Wn = w_nbr  + l * 262144;
    const float* bl = b_gnn  + l * 512;
    agg_kernel<<<4096, 256, 0, stream>>>(hA, nbr, den, agg);
    gnn_gemm_kernel<<<256, 256, 0, stream>>>(hA, agg, Wl, Wn, part);
    float* hout = (l == 3) ? (float*)d_out : hA;
    gnn_reduce_kernel<<<1024, 256, 0, stream>>>(part, bl, hout);
  }
}

// Round 2
// 532.367 us; speedup vs baseline: 1.6953x; 1.6953x over previous
//
#include <hip/hip_runtime.h>

// WinGNN: conv-encode (fp16 MFMA implicit-im2col) -> radius-KNN -> 4-layer GNN (fp32).
//
// Workspace layout (bytes):
//   wfrag @ 0        : 12288 fp16 conv-weight fragments (40960 B slot)
//   enc   @ 40960    : 2048x64 f32 (524288 B)
//   hA    @ 565248   : 2048x512 f32 (4 MB)
//   agg   @ 4759552  : 2048x512 f32 (4 MB)
//   part  @ 8953856  : 4x2048x512 f32 (16 MB) split-K partials
//   nbr   @ 25731072 : 2048x5 int (40960 B slot)
//   den   @ 25772032 : 2048 f32

#define NNODES 2048

typedef __attribute__((ext_vector_type(8))) _Float16 half8;
typedef __attribute__((ext_vector_type(16))) float f32x16;

// ---------- prep: conv_w [64][3][7][7] f32 -> MFMA B-fragments fp16 ----------
// k-order: k = 16*kb + 8*hi + j ; group g = 2*kb + hi = ic*7+ky (g<21), kx = j (j<7).
// frag flat layout: (((ct*12 + kb)*64 + lane)*8 + j), value = W[c=32ct+(lane&31)][g][kx]
__global__ __launch_bounds__(256) void prep_wfrag_kernel(
    const float* __restrict__ w, ushort* __restrict__ wfrag) {
  int i = blockIdx.x * 256 + threadIdx.x;
  if (i >= 12288) return;
  int j = i & 7;
  int l = (i >> 3) & 63;
  int q = i >> 9;            // ct*12 + kb
  int kb = q % 12, ct = q / 12;
  int g = 2 * kb + (l >> 5);
  int c = 32 * ct + (l & 31);
  float val = 0.f;
  if (g < 21 && j < 7) val = w[c * 147 + g * 7 + j];
  wfrag[i] = __builtin_bit_cast(ushort, (_Float16)val);
}

__device__ inline uint pack2h(float x, float y) {
  ushort a = __builtin_bit_cast(ushort, (_Float16)x);
  ushort b = __builtin_bit_cast(ushort, (_Float16)y);
  return (uint)a | ((uint)b << 16);
}

// ---------- conv7x7 s2 SAME + bias + relu + global avg pool, fp16 MFMA ----------
// 1 block/image, 4 waves. Wave w: pixel-tiles pt=8w..8w+7 (each = output row pt, 32 ox),
// computes all 64 channels (2 col-tiles of 32) via 12 chained 32x32x16 MFMAs each.
__global__ __launch_bounds__(256) void conv_pool_kernel(
    const float* __restrict__ imgs, const ushort* __restrict__ wfrag,
    const float* __restrict__ cb, float* __restrict__ enc) {
  __shared__ ushort s_img[14904];   // fp16 padded image [3][69][72], halo zeros
  __shared__ float s_pool[64];
  const int n = blockIdx.x;
  const int tid = threadIdx.x;
  const int lane = tid & 63;
  const int w = tid >> 6;
  const int hi = lane >> 5;
  const int lo = lane & 31;

  // B fragments: 24 coalesced 16B loads per lane (L3-resident, shared by all blocks)
  half8 bf[24];
  const half8* wf = (const half8*)wfrag;
#pragma unroll
  for (int q = 0; q < 24; ++q) bf[q] = wf[q * 64 + lane];

  // zero LDS (covers halo) + pool init
  int4 z = {0, 0, 0, 0};
  for (int i = tid; i < 1863; i += 256) ((int4*)s_img)[i] = z;
  if (tid < 64) s_pool[tid] = 0.f;
  __syncthreads();

  // stage image fp32 -> fp16 LDS, padded (+2,+2)
  const float4* src = (const float4*)(imgs + (size_t)n * 12288);
  for (int i = tid; i < 3072; i += 256) {
    float4 v = src[i];
    int e = i << 2;
    int c = e >> 12;
    int rem = e & 4095;
    int y = rem >> 6, x = rem & 63;
    int d = (c * 69 + y + 2) * 72 + x + 2;   // element index, d%4==2
    ((uint*)s_img)[d >> 1] = pack2h(v.x, v.y);
    ((uint*)s_img)[(d >> 1) + 1] = pack2h(v.z, v.w);
  }

  // per-lane A-fragment base byte offsets (row = ic*69 + ky for g=2kb+hi; x-start 2*lo)
  int boff[12];
#pragma unroll
  for (int kb = 0; kb < 12; ++kb) {
    int g = 2 * kb + hi;
    if (g > 20) g = 20;               // padding groups: B is zero, read valid memory
    int ic = g / 7, ky = g - ic * 7;
    boff[kb] = (ic * 69 + ky) * 144 + 4 * lo;
  }
  const float bias0 = cb[lo];
  const float bias1 = cb[32 + lo];
  float pool0 = 0.f, pool1 = 0.f;
  __syncthreads();

  const char* sb = (const char*)s_img;
  for (int t = 0; t < 8; ++t) {
    int pt = (w << 3) + t;
    int tadd = pt * 288;
    f32x16 acc0 = {}, acc1 = {};
#pragma unroll
    for (int kb = 0; kb < 12; ++kb) {
      const char* p = sb + boff[kb] + tadd;
      union { half8 v; uint u[4]; } af;
      af.u[0] = *(const uint*)(p);
      af.u[1] = *(const uint*)(p + 4);
      af.u[2] = *(const uint*)(p + 8);
      af.u[3] = *(const uint*)(p + 12);
      acc0 = __builtin_amdgcn_mfma_f32_32x32x16_f16(af.v, bf[kb], acc0, 0, 0, 0);
      acc1 = __builtin_amdgcn_mfma_f32_32x32x16_f16(af.v, bf[12 + kb], acc1, 0, 0, 0);
    }
    float s0 = 0.f, s1 = 0.f;
#pragma unroll
    for (int r = 0; r < 16; ++r) {
      s0 += fmaxf(acc0[r] + bias0, 0.f);
      s1 += fmaxf(acc1[r] + bias1, 0.f);
    }
    pool0 += s0;
    pool1 += s1;
  }
  pool0 += __shfl_xor(pool0, 32);
  pool1 += __shfl_xor(pool1, 32);
  if (lane < 32) {
    atomicAdd(&s_pool[lo], pool0);
    atomicAdd(&s_pool[32 + lo], pool1);
  }
  __syncthreads();
  if (tid < 64) enc[n * 64 + tid] = s_pool[tid] * (1.f / 1024.f);
}

// ---------- proj: relu(enc[2048,64] @ pw[64,512] + pb) -> h[2048,512] ----------
__global__ __launch_bounds__(256) void proj_kernel(
    const float* __restrict__ enc, const float* __restrict__ pw,
    const float* __restrict__ pb, float* __restrict__ h) {
  int c = ((blockIdx.x & 1) << 8) | threadIdx.x;
  int r0 = (blockIdx.x >> 1) << 3;
  float bias = pb[c];
  float acc[8];
#pragma unroll
  for (int r = 0; r < 8; ++r) acc[r] = bias;
#pragma unroll 4
  for (int k = 0; k < 64; ++k) {
    float w = pw[k * 512 + c];
#pragma unroll
    for (int r = 0; r < 8; ++r) acc[r] = fmaf(enc[(r0 + r) * 64 + k], w, acc[r]);
  }
#pragma unroll
  for (int r = 0; r < 8; ++r) h[(r0 + r) * 512 + c] = fmaxf(acc[r], 0.f);
}

// ---------- radius-KNN: top-5 nearest within r2<=2, no self ----------
__global__ __launch_bounds__(256) void knn_kernel(
    const float* __restrict__ pos, int* __restrict__ nbr, float* __restrict__ den) {
  int i = blockIdx.x * 256 + threadIdx.x;
  float2 p = ((const float2*)pos)[i];
  float px = p.x * 32.f, py = p.y * 32.f;
  float bd[5] = {1e30f, 1e30f, 1e30f, 1e30f, 1e30f};
  int   bi[5] = {-1, -1, -1, -1, -1};
  for (int j = 0; j < NNODES; ++j) {
    float2 q = ((const float2*)pos)[j];   // wave-uniform -> scalar load
    float dx = q.x * 32.f - px, dy = q.y * 32.f - py;
    float d2 = dx * dx + dy * dy;
    if (d2 <= 2.0f && j != i && d2 < bd[4]) {
      float nd = d2; int ni = j;
#pragma unroll
      for (int k = 0; k < 5; ++k) {
        bool s = nd < bd[k];
        float td = bd[k]; int ti = bi[k];
        bd[k] = s ? nd : td;  bi[k] = s ? ni : ti;
        nd = s ? td : nd;     ni = s ? ti : ni;
      }
    }
  }
  int cnt = 0;
#pragma unroll
  for (int k = 0; k < 5; ++k) cnt += (bi[k] >= 0);
#pragma unroll
  for (int k = 0; k < 5; ++k) nbr[i * 5 + k] = bi[k];
  den[i] = (float)(cnt > 0 ? cnt : 1);
}

// ---------- agg[i][d] = sum_valid h[nbr][d] / den[i] ----------
__global__ __launch_bounds__(256) void agg_kernel(
    const float* __restrict__ h, const int* __restrict__ nbr,
    const float* __restrict__ den, float* __restrict__ agg) {
  int i = blockIdx.x >> 1;
  int d = ((blockIdx.x & 1) << 8) + threadIdx.x;
  float s = 0.f;
#pragma unroll
  for (int k = 0; k < 5; ++k) {
    int j = nbr[i * 5 + k];               // wave-uniform
    if (j >= 0) s += h[j * 512 + d];      // coalesced
  }
  agg[i * 512 + d] = s / den[i];
}

// ---------- GNN GEMM: part[split] = h@Ws + agg@Wn (128x128 tile, 8x8 micro, splitK=4) ----------
__global__ __launch_bounds__(256) void gnn_gemm_kernel(
    const float* __restrict__ hmat, const float* __restrict__ agg,
    const float* __restrict__ wself, const float* __restrict__ wnbr,
    float* __restrict__ part) {
  __shared__ float s_a[16][132];   // A-tile transposed [k][r], padded
  __shared__ float s_b[16][128];
  int bid = blockIdx.x;
  int split = bid & 3;
  int bn = (bid >> 2) & 3;
  int bm = bid >> 4;
  int r0 = bm << 7, c0 = bn << 7, k0 = split << 7;
  int tid = threadIdx.x;
  int ty = tid >> 4, tx = tid & 15;
  float acc[8][8] = {};

  int ar = tid >> 1, ak = (tid & 1) << 3;     // A load: 128 rows x 16 k
  int bk = tid >> 5, bc = (tid & 31) << 2;    // B load: 16 k x 128 cols

  for (int phase = 0; phase < 2; ++phase) {
    const float* A = phase ? agg : hmat;
    const float* W = phase ? wnbr : wself;
    for (int kt = 0; kt < 128; kt += 16) {
      int kb2 = k0 + kt;
      float4 v0 = *(const float4*)&A[(r0 + ar) * 512 + kb2 + ak];
      float4 v1 = *(const float4*)&A[(r0 + ar) * 512 + kb2 + ak + 4];
      float4 w0 = *(const float4*)&W[(kb2 + bk) * 512 + c0 + bc];
      float4 w1 = *(const float4*)&W[(kb2 + bk + 8) * 512 + c0 + bc];
      __syncthreads();
      s_a[ak + 0][ar] = v0.x; s_a[ak + 1][ar] = v0.y;
      s_a[ak + 2][ar] = v0.z; s_a[ak + 3][ar] = v0.w;
      s_a[ak + 4][ar] = v1.x; s_a[ak + 5][ar] = v1.y;
      s_a[ak + 6][ar] = v1.z; s_a[ak + 7][ar] = v1.w;
      *(float4*)&s_b[bk][bc] = w0;
      *(float4*)&s_b[bk + 8][bc] = w1;
      __syncthreads();
#pragma unroll
      for (int kk = 0; kk < 16; ++kk) {
        float a[8], b[8];
        *(float4*)&a[0] = *(const float4*)&s_a[kk][ty << 3];
        *(float4*)&a[4] = *(const float4*)&s_a[kk][(ty << 3) + 4];
#pragma unroll
        for (int j = 0; j < 8; ++j) b[j] = s_b[kk][tx + (j << 4)];
#pragma unroll
        for (int ii = 0; ii < 8; ++ii)
#pragma unroll
          for (int j = 0; j < 8; ++j)
            acc[ii][j] = fmaf(a[ii], b[j], acc[ii][j]);
      }
    }
  }
  __syncthreads();
  float* dst = part + (size_t)split * (NNODES * 512);
#pragma unroll
  for (int ii = 0; ii < 8; ++ii) {
    int r = r0 + (ty << 3) + ii;
#pragma unroll
    for (int j = 0; j < 8; ++j)
      dst[r * 512 + c0 + tx + (j << 4)] = acc[ii][j];
  }
}

// ---------- reduce splits + bias + relu ----------
__global__ __launch_bounds__(256) void gnn_reduce_kernel(
    const float* __restrict__ part, const float* __restrict__ bg,
    float* __restrict__ hout) {
  int i = blockIdx.x * 256 + threadIdx.x;   // float4 index, 262144 total
  const float4* p = (const float4*)part;
  float4 a = p[i];
  float4 b = p[i + 262144];
  float4 c = p[i + 524288];
  float4 d = p[i + 786432];
  float4 bb = ((const float4*)bg)[i & 127];
  float4 o;
  o.x = fmaxf(a.x + b.x + c.x + d.x + bb.x, 0.f);
  o.y = fmaxf(a.y + b.y + c.y + d.y + bb.y, 0.f);
  o.z = fmaxf(a.z + b.z + c.z + d.z + bb.z, 0.f);
  o.w = fmaxf(a.w + b.w + c.w + d.w + bb.w, 0.f);
  ((float4*)hout)[i] = o;
}

extern "C" void kernel_launch(void* const* d_in, const int* in_sizes, int n_in,
                              void* d_out, int out_size, void* d_ws, size_t ws_size,
                              hipStream_t stream) {
  const float* imgs   = (const float*)d_in[0];
  const float* pos    = (const float*)d_in[1];
  const float* conv_w = (const float*)d_in[2];
  const float* conv_b = (const float*)d_in[3];
  const float* proj_w = (const float*)d_in[4];
  const float* proj_b = (const float*)d_in[5];
  const float* w_self = (const float*)d_in[6];
  const float* w_nbr  = (const float*)d_in[7];
  const float* b_gnn  = (const float*)d_in[8];

  char* ws = (char*)d_ws;
  ushort* wfrag = (ushort*)(ws);
  float* enc  = (float*)(ws + 40960);
  float* hA   = (float*)(ws + 40960 + 524288);
  float* agg  = (float*)(ws + 40960 + 524288 + 4194304);
  float* part = (float*)(ws + 40960 + 524288 + 2 * 4194304);
  int*   nbr  = (int*)  (ws + 40960 + 524288 + 2 * 4194304 + 16777216);
  float* den  = (float*)(ws + 40960 + 524288 + 2 * 4194304 + 16777216 + 40960);

  prep_wfrag_kernel<<<48, 256, 0, stream>>>(conv_w, wfrag);
  knn_kernel<<<8, 256, 0, stream>>>(pos, nbr, den);
  conv_pool_kernel<<<2048, 256, 0, stream>>>(imgs, wfrag, conv_b, enc);
  proj_kernel<<<512, 256, 0, stream>>>(enc, proj_w, proj_b, hA);

  for (int l = 0; l < 4; ++l) {
    const float* Wl = w_self + l * 262144;
    const float* Wn = w_nbr  + l * 262144;
    const float* bl = b_gnn  + l * 512;
    agg_kernel<<<4096, 256, 0, stream>>>(hA, nbr, den, agg);
    gnn_gemm_kernel<<<256, 256, 0, stream>>>(hA, agg, Wl, Wn, part);
    float* hout = (l == 3) ? (float*)d_out : hA;
    gnn_reduce_kernel<<<1024, 256, 0, stream>>>(part, bl, hout);
  }
}

// Round 3
// 167.415 us; speedup vs baseline: 5.3910x; 3.1799x over previous
//
#include <hip/hip_runtime.h>

// WinGNN: conv-encode (fp16 MFMA) -> radius-KNN (parallel) -> 4-layer GNN (fp16 MFMA).
//
// Workspace layout (bytes):
//   wfrag @ 0        : 12288 fp16 conv-weight fragments (32768 B slot)
//   enc   @ 32768    : 2048x64 f32 (524288)
//   h16a  @ 557056   : 2048x512 fp16 (2 MB)
//   h16b  @ 2654208  : 2048x512 fp16 (2 MB)
//   agg16 @ 4751360  : 2048x512 fp16 (2 MB)
//   wT16  @ 6848512  : 8x512x512 fp16 (4 MB)  [m<4: w_self[l] ; m>=4: w_nbr[l]] as [n][k]
//   nbr   @ 11042816 : 2048x5 int (40960 slot)
//   den   @ 11083776 : 2048 f32

#define NNODES 2048

typedef __attribute__((ext_vector_type(8))) _Float16 half8;
typedef __attribute__((ext_vector_type(16))) float f32x16;

// ---------- prep: conv_w [64][3][7][7] f32 -> MFMA B-fragments fp16 ----------
__global__ __launch_bounds__(256) void prep_wfrag_kernel(
    const float* __restrict__ w, ushort* __restrict__ wfrag) {
  int i = blockIdx.x * 256 + threadIdx.x;
  if (i >= 12288) return;
  int j = i & 7;
  int l = (i >> 3) & 63;
  int q = i >> 9;            // ct*12 + kb
  int kb = q % 12, ct = q / 12;
  int g = 2 * kb + (l >> 5);
  int c = 32 * ct + (l & 31);
  float val = 0.f;
  if (g < 21 && j < 7) val = w[c * 147 + g * 7 + j];
  wfrag[i] = __builtin_bit_cast(ushort, (_Float16)val);
}

// ---------- prep: w_self/w_nbr [k][n] f32 -> wT16 [m][n][k] fp16 ----------
__global__ __launch_bounds__(256) void prep_wT_kernel(
    const float* __restrict__ wsrc_s, const float* __restrict__ wsrc_n,
    ushort* __restrict__ wT) {
  __shared__ float s[64][65];
  int bid = blockIdx.x;                 // 512 = 8 mats x 8 kt x 8 nt
  int m = bid >> 6, kt = (bid >> 3) & 7, nt = bid & 7;
  const float* in = (m < 4) ? (wsrc_s + m * 262144) : (wsrc_n + (m - 4) * 262144);
  ushort* out = wT + m * 262144;
  int t = threadIdx.x;
  int k0 = kt << 6, n0 = nt << 6;
#pragma unroll
  for (int rep = 0; rep < 4; ++rep) {
    int row = (rep << 4) + (t >> 4);
    int c4 = (t & 15) << 2;
    float4 v = *(const float4*)&in[(k0 + row) * 512 + n0 + c4];
    s[row][c4] = v.x; s[row][c4 + 1] = v.y; s[row][c4 + 2] = v.z; s[row][c4 + 3] = v.w;
  }
  __syncthreads();
#pragma unroll
  for (int rep = 0; rep < 4; ++rep) {
    int n = (rep << 4) + (t >> 4);
    int k4 = (t & 15) << 2;
    ushort4 o;
    o.x = __builtin_bit_cast(ushort, (_Float16)s[k4 + 0][n]);
    o.y = __builtin_bit_cast(ushort, (_Float16)s[k4 + 1][n]);
    o.z = __builtin_bit_cast(ushort, (_Float16)s[k4 + 2][n]);
    o.w = __builtin_bit_cast(ushort, (_Float16)s[k4 + 3][n]);
    *(ushort4*)&out[(n0 + n) * 512 + k0 + k4] = o;
  }
}

__device__ inline uint pack2h(float x, float y) {
  ushort a = __builtin_bit_cast(ushort, (_Float16)x);
  ushort b = __builtin_bit_cast(ushort, (_Float16)y);
  return (uint)a | ((uint)b << 16);
}

// ---------- conv7x7 s2 SAME + bias + relu + global avg pool, fp16 MFMA ----------
__global__ __launch_bounds__(256) void conv_pool_kernel(
    const float* __restrict__ imgs, const ushort* __restrict__ wfrag,
    const float* __restrict__ cb, float* __restrict__ enc) {
  __shared__ ushort s_img[14904];   // fp16 padded image [3][69][72], halo zeros
  __shared__ float s_pool[64];
  const int n = blockIdx.x;
  const int tid = threadIdx.x;
  const int lane = tid & 63;
  const int w = tid >> 6;
  const int hi = lane >> 5;
  const int lo = lane & 31;

  half8 bf[24];
  const half8* wf = (const half8*)wfrag;
#pragma unroll
  for (int q = 0; q < 24; ++q) bf[q] = wf[q * 64 + lane];

  int4 z = {0, 0, 0, 0};
  for (int i = tid; i < 1863; i += 256) ((int4*)s_img)[i] = z;
  if (tid < 64) s_pool[tid] = 0.f;
  __syncthreads();

  const float4* src = (const float4*)(imgs + (size_t)n * 12288);
  for (int i = tid; i < 3072; i += 256) {
    float4 v = src[i];
    int e = i << 2;
    int c = e >> 12;
    int rem = e & 4095;
    int y = rem >> 6, x = rem & 63;
    int d = (c * 69 + y + 2) * 72 + x + 2;
    ((uint*)s_img)[d >> 1] = pack2h(v.x, v.y);
    ((uint*)s_img)[(d >> 1) + 1] = pack2h(v.z, v.w);
  }

  int boff[12];
#pragma unroll
  for (int kb = 0; kb < 12; ++kb) {
    int g = 2 * kb + hi;
    if (g > 20) g = 20;
    int ic = g / 7, ky = g - ic * 7;
    boff[kb] = (ic * 69 + ky) * 144 + 4 * lo;
  }
  const float bias0 = cb[lo];
  const float bias1 = cb[32 + lo];
  float pool0 = 0.f, pool1 = 0.f;
  __syncthreads();

  const char* sb = (const char*)s_img;
  for (int t = 0; t < 8; ++t) {
    int pt = (w << 3) + t;
    int tadd = pt * 288;
    f32x16 acc0 = {}, acc1 = {};
#pragma unroll
    for (int kb = 0; kb < 12; ++kb) {
      const char* p = sb + boff[kb] + tadd;
      union { half8 v; uint u[4]; } af;
      af.u[0] = *(const uint*)(p);
      af.u[1] = *(const uint*)(p + 4);
      af.u[2] = *(const uint*)(p + 8);
      af.u[3] = *(const uint*)(p + 12);
      acc0 = __builtin_amdgcn_mfma_f32_32x32x16_f16(af.v, bf[kb], acc0, 0, 0, 0);
      acc1 = __builtin_amdgcn_mfma_f32_32x32x16_f16(af.v, bf[12 + kb], acc1, 0, 0, 0);
    }
    float s0 = 0.f, s1 = 0.f;
#pragma unroll
    for (int r = 0; r < 16; ++r) {
      s0 += fmaxf(acc0[r] + bias0, 0.f);
      s1 += fmaxf(acc1[r] + bias1, 0.f);
    }
    pool0 += s0;
    pool1 += s1;
  }
  pool0 += __shfl_xor(pool0, 32);
  pool1 += __shfl_xor(pool1, 32);
  if (lane < 32) {
    atomicAdd(&s_pool[lo], pool0);
    atomicAdd(&s_pool[32 + lo], pool1);
  }
  __syncthreads();
  if (tid < 64) enc[n * 64 + tid] = s_pool[tid] * (1.f / 1024.f);
}

// ---------- proj: relu(enc @ pw + pb) -> h16 [2048][512] fp16 ----------
__global__ __launch_bounds__(256) void proj_kernel(
    const float* __restrict__ enc, const float* __restrict__ pw,
    const float* __restrict__ pb, ushort* __restrict__ h16) {
  int c = ((blockIdx.x & 1) << 8) | threadIdx.x;
  int r0 = (blockIdx.x >> 1) << 3;
  float bias = pb[c];
  float acc[8];
#pragma unroll
  for (int r = 0; r < 8; ++r) acc[r] = bias;
#pragma unroll 4
  for (int k = 0; k < 64; ++k) {
    float w = pw[k * 512 + c];
#pragma unroll
    for (int r = 0; r < 8; ++r) acc[r] = fmaf(enc[(r0 + r) * 64 + k], w, acc[r]);
  }
#pragma unroll
  for (int r = 0; r < 8; ++r)
    h16[(r0 + r) * 512 + c] = __builtin_bit_cast(ushort, (_Float16)fmaxf(acc[r], 0.f));
}

// ---------- radius-KNN: one block per node ----------
__global__ __launch_bounds__(256) void knn_kernel(
    const float* __restrict__ pos, int* __restrict__ nbr, float* __restrict__ den) {
  __shared__ float s_d2[NNODES];
  __shared__ int s_idx[NNODES];
  __shared__ int s_cnt;
  const int i = blockIdx.x;
  const int tid = threadIdx.x;
  if (tid == 0) s_cnt = 0;
  __syncthreads();
  const float px = pos[2 * i] * 32.f, py = pos[2 * i + 1] * 32.f;
#pragma unroll
  for (int r = 0; r < 8; ++r) {
    int j = tid + (r << 8);
    float2 q = ((const float2*)pos)[j];
    float dx = q.x * 32.f - px, dy = q.y * 32.f - py;
    float d2 = dx * dx + dy * dy;
    if (d2 <= 2.0f && j != i) {
      int slot = atomicAdd(&s_cnt, 1);
      s_d2[slot] = d2;
      s_idx[slot] = j;
    }
  }
  __syncthreads();
  if (tid < 64) {
    const int lane = tid;
    const int cnt = s_cnt;
    int nf = 0;
#pragma unroll
    for (int k = 0; k < 5; ++k) {
      float best = 1e30f;
      int bslot = 0x7fffffff;
      for (int e = lane; e < cnt; e += 64) {
        float d = s_d2[e];
        if (d < best) { best = d; bslot = e; }
      }
#pragma unroll
      for (int off = 1; off < 64; off <<= 1) {
        float od = __shfl_xor(best, off);
        int os = __shfl_xor(bslot, off);
        if (od < best || (od == best && os < bslot)) { best = od; bslot = os; }
      }
      bool got = (best < 1e30f);
      if (lane == 0) nbr[i * 5 + k] = got ? s_idx[bslot] : -1;
      if (got) { s_d2[bslot] = 1e30f; ++nf; }
    }
    if (lane == 0) den[i] = (float)(nf > 0 ? nf : 1);
  }
}

// ---------- agg16[i][d] = mean of valid h16[nbr][d] ----------
__global__ __launch_bounds__(256) void agg_kernel(
    const ushort* __restrict__ h16, const int* __restrict__ nbr,
    const float* __restrict__ den, ushort* __restrict__ agg16) {
  int i = blockIdx.x >> 1;
  int d = ((blockIdx.x & 1) << 8) + threadIdx.x;
  const _Float16* hp = (const _Float16*)h16;
  float s = 0.f;
#pragma unroll
  for (int k = 0; k < 5; ++k) {
    int j = nbr[i * 5 + k];
    if (j >= 0) s += (float)hp[j * 512 + d];
  }
  agg16[i * 512 + d] = __builtin_bit_cast(ushort, (_Float16)(s / den[i]));
}

// ---------- GNN layer: out = relu(h@Ws + agg@Wn + b), fp16 MFMA ----------
// 256 blocks (32 bm x 8 bn), 64x64 tile, BK=64, glds double-buffer.
// LDS granule layout per buffer: sA [ksup][row][8] at 0, sB [ksup][col][8] at ushort 4096.
__global__ __launch_bounds__(256) void gnn_gemm_kernel(
    const ushort* __restrict__ A0, const ushort* __restrict__ A1,
    const ushort* __restrict__ B0, const ushort* __restrict__ B1,
    const float* __restrict__ bias, ushort* __restrict__ hout,
    float* __restrict__ fout, int final_layer) {
  __shared__ ushort s_lds[2][8192];
  const int tid = threadIdx.x;
  const int lane = tid & 63;
  const int hi = lane >> 5, lo = lane & 31;
  const int wu = __builtin_amdgcn_readfirstlane(tid >> 6);
  const int wr = wu >> 1, wc = wu & 1;
  const int bm = blockIdx.x >> 3, bn = blockIdx.x & 7;
  const int r0 = bm << 6, c0 = bn << 6;

  auto STAGE = [&](int buf, int it) {
    const ushort* A = (it & 8) ? A1 : A0;
    const ushort* B = (it & 8) ? B1 : B0;
    int k0 = (it & 7) << 6;
    const ushort* a0 = A + (r0 + lane) * 512 + k0 + 8 * wu;
    const ushort* b0 = B + (c0 + lane) * 512 + k0 + 8 * wu;
    ushort* lb = &s_lds[buf][wu << 9];
    __builtin_amdgcn_global_load_lds(
        (const __attribute__((address_space(1))) void*)(a0),
        (__attribute__((address_space(3))) void*)(lb), 16, 0, 0);
    __builtin_amdgcn_global_load_lds(
        (const __attribute__((address_space(1))) void*)(a0 + 32),
        (__attribute__((address_space(3))) void*)(lb + 2048), 16, 0, 0);
    __builtin_amdgcn_global_load_lds(
        (const __attribute__((address_space(1))) void*)(b0),
        (__attribute__((address_space(3))) void*)(lb + 4096), 16, 0, 0);
    __builtin_amdgcn_global_load_lds(
        (const __attribute__((address_space(1))) void*)(b0 + 32),
        (__attribute__((address_space(3))) void*)(lb + 6144), 16, 0, 0);
  };

  f32x16 acc = {};
  STAGE(0, 0);
  __syncthreads();                       // compiler drains vmcnt before barrier
  int cur = 0;
  for (int it = 0; it < 16; ++it) {
    if (it < 15) STAGE(cur ^ 1, it + 1);
    const half8* pA = (const half8*)&s_lds[cur][0];
    const half8* pB = (const half8*)&s_lds[cur][4096];
#pragma unroll
    for (int ks = 0; ks < 4; ++ks) {
      half8 af = pA[(2 * ks + hi) * 64 + 32 * wr + lo];
      half8 bfr = pB[(2 * ks + hi) * 64 + 32 * wc + lo];
      acc = __builtin_amdgcn_mfma_f32_32x32x16_f16(af, bfr, acc, 0, 0, 0);
    }
    __syncthreads();
    cur ^= 1;
  }

  const int col = c0 + 32 * wc + lo;
  const float b = bias[col];
#pragma unroll
  for (int r = 0; r < 16; ++r) {
    int row = r0 + 32 * wr + (r & 3) + ((r >> 2) << 3) + (hi << 2);
    float v = fmaxf(acc[r] + b, 0.f);
    if (final_layer) fout[row * 512 + col] = v;
    else hout[row * 512 + col] = __builtin_bit_cast(ushort, (_Float16)v);
  }
}

extern "C" void kernel_launch(void* const* d_in, const int* in_sizes, int n_in,
                              void* d_out, int out_size, void* d_ws, size_t ws_size,
                              hipStream_t stream) {
  const float* imgs   = (const float*)d_in[0];
  const float* pos    = (const float*)d_in[1];
  const float* conv_w = (const float*)d_in[2];
  const float* conv_b = (const float*)d_in[3];
  const float* proj_w = (const float*)d_in[4];
  const float* proj_b = (const float*)d_in[5];
  const float* w_self = (const float*)d_in[6];
  const float* w_nbr  = (const float*)d_in[7];
  const float* b_gnn  = (const float*)d_in[8];

  char* ws = (char*)d_ws;
  ushort* wfrag = (ushort*)(ws);
  float*  enc   = (float*) (ws + 32768);
  ushort* h16a  = (ushort*)(ws + 557056);
  ushort* h16b  = (ushort*)(ws + 2654208);
  ushort* agg16 = (ushort*)(ws + 4751360);
  ushort* wT16  = (ushort*)(ws + 6848512);
  int*    nbr   = (int*)   (ws + 11042816);
  float*  den   = (float*) (ws + 11083776);

  prep_wfrag_kernel<<<48, 256, 0, stream>>>(conv_w, wfrag);
  prep_wT_kernel<<<512, 256, 0, stream>>>(w_self, w_nbr, wT16);
  knn_kernel<<<NNODES, 256, 0, stream>>>(pos, nbr, den);
  conv_pool_kernel<<<NNODES, 256, 0, stream>>>(imgs, wfrag, conv_b, enc);
  proj_kernel<<<512, 256, 0, stream>>>(enc, proj_w, proj_b, h16a);

  for (int l = 0; l < 4; ++l) {
    ushort* hin  = (l & 1) ? h16b : h16a;
    ushort* hnew = (l & 1) ? h16a : h16b;
    agg_kernel<<<4096, 256, 0, stream>>>(hin, nbr, den, agg16);
    gnn_gemm_kernel<<<256, 256, 0, stream>>>(
        hin, agg16, wT16 + l * 262144, wT16 + (4 + l) * 262144,
        b_gnn + l * 512, hnew, (float*)d_out, (l == 3) ? 1 : 0);
  }
}

// Round 4
// 160.309 us; speedup vs baseline: 5.6299x; 1.0443x over previous
//
#include <hip/hip_runtime.h>

// WinGNN: conv-encode (fp16 MFMA) -> radius-KNN (parallel) -> 4-layer GNN (fp16 MFMA, fused dual-GEMM).
//
// Workspace layout (bytes):
//   wfrag @ 0        : 12288 fp16 conv-weight fragments (32768 B slot)
//   enc   @ 32768    : 2048x64 f32 (524288)
//   h16a  @ 557056   : 2048x512 fp16 (2 MB)
//   h16b  @ 2654208  : 2048x512 fp16 (2 MB)
//   agg16 @ 4751360  : 2048x512 fp16 (2 MB)
//   wT16  @ 6848512  : 8x512x512 fp16 (4 MB)  [m<4: w_self[l] ; m>=4: w_nbr[l]] as [n][k]
//   nbr   @ 11042816 : 2048x5 int (40960 slot)
//   den   @ 11083776 : 2048 f32 (stores 1/count)

#define NNODES 2048

typedef __attribute__((ext_vector_type(8))) _Float16 half8;
typedef __attribute__((ext_vector_type(16))) float f32x16;

// ---------- prep: conv_w [64][3][7][7] f32 -> MFMA B-fragments fp16 ----------
__global__ __launch_bounds__(256) void prep_wfrag_kernel(
    const float* __restrict__ w, ushort* __restrict__ wfrag) {
  int i = blockIdx.x * 256 + threadIdx.x;
  if (i >= 12288) return;
  int j = i & 7;
  int l = (i >> 3) & 63;
  int q = i >> 9;            // ct*12 + kb
  int kb = q % 12, ct = q / 12;
  int g = 2 * kb + (l >> 5);
  int c = 32 * ct + (l & 31);
  float val = 0.f;
  if (g < 21 && j < 7) val = w[c * 147 + g * 7 + j];
  wfrag[i] = __builtin_bit_cast(ushort, (_Float16)val);
}

// ---------- prep: w_self/w_nbr [k][n] f32 -> wT16 [m][n][k] fp16 ----------
__global__ __launch_bounds__(256) void prep_wT_kernel(
    const float* __restrict__ wsrc_s, const float* __restrict__ wsrc_n,
    ushort* __restrict__ wT) {
  __shared__ float s[64][65];
  int bid = blockIdx.x;                 // 512 = 8 mats x 8 kt x 8 nt
  int m = bid >> 6, kt = (bid >> 3) & 7, nt = bid & 7;
  const float* in = (m < 4) ? (wsrc_s + m * 262144) : (wsrc_n + (m - 4) * 262144);
  ushort* out = wT + m * 262144;
  int t = threadIdx.x;
  int k0 = kt << 6, n0 = nt << 6;
#pragma unroll
  for (int rep = 0; rep < 4; ++rep) {
    int row = (rep << 4) + (t >> 4);
    int c4 = (t & 15) << 2;
    float4 v = *(const float4*)&in[(k0 + row) * 512 + n0 + c4];
    s[row][c4] = v.x; s[row][c4 + 1] = v.y; s[row][c4 + 2] = v.z; s[row][c4 + 3] = v.w;
  }
  __syncthreads();
#pragma unroll
  for (int rep = 0; rep < 4; ++rep) {
    int n = (rep << 4) + (t >> 4);
    int k4 = (t & 15) << 2;
    ushort4 o;
    o.x = __builtin_bit_cast(ushort, (_Float16)s[k4 + 0][n]);
    o.y = __builtin_bit_cast(ushort, (_Float16)s[k4 + 1][n]);
    o.z = __builtin_bit_cast(ushort, (_Float16)s[k4 + 2][n]);
    o.w = __builtin_bit_cast(ushort, (_Float16)s[k4 + 3][n]);
    *(ushort4*)&out[(n0 + n) * 512 + k0 + k4] = o;
  }
}

__device__ inline uint pack2h(float x, float y) {
  ushort a = __builtin_bit_cast(ushort, (_Float16)x);
  ushort b = __builtin_bit_cast(ushort, (_Float16)y);
  return (uint)a | ((uint)b << 16);
}

// ---------- conv7x7 s2 SAME + bias + relu + global avg pool, fp16 MFMA ----------
// 1 block/image, 4 waves. Wave w owns output rows w*8..w*8+7, processed in
// pairs -> 4 independent MFMA chains; inner loop has zero address VALU
// (per-lane base regs + compile-time ds offsets).
__global__ __launch_bounds__(256) void conv_pool_kernel(
    const float* __restrict__ imgs, const ushort* __restrict__ wfrag,
    const float* __restrict__ cb, float* __restrict__ enc) {
  __shared__ ushort s_img[14904];   // fp16 padded image [3][69][72], halo zeros
  __shared__ float s_pool[64];
  const int n = blockIdx.x;
  const int tid = threadIdx.x;
  const int lane = tid & 63;
  const int w = tid >> 6;
  const int hi = lane >> 5;
  const int lo = lane & 31;

  half8 bf[24];
  const half8* wf = (const half8*)wfrag;
#pragma unroll
  for (int q = 0; q < 24; ++q) bf[q] = wf[q * 64 + lane];

  int4 z = {0, 0, 0, 0};
  for (int i = tid; i < 1863; i += 256) ((int4*)s_img)[i] = z;
  if (tid < 64) s_pool[tid] = 0.f;
  __syncthreads();

  const float4* src = (const float4*)(imgs + (size_t)n * 12288);
  for (int i = tid; i < 3072; i += 256) {
    float4 v = src[i];
    int e = i << 2;
    int c = e >> 12;
    int rem = e & 4095;
    int y = rem >> 6, x = rem & 63;
    int d = (c * 69 + y + 2) * 72 + x + 2;
    ((uint*)s_img)[d >> 1] = pack2h(v.x, v.y);
    ((uint*)s_img)[(d >> 1) + 1] = pack2h(v.z, v.w);
  }

  // per-lane byte offsets into s_img; wave row base baked in
  int aoff[12];
#pragma unroll
  for (int kb = 0; kb < 12; ++kb) {
    int g = 2 * kb + hi;
    if (g > 20) g = 20;               // padding group: B is zero, read valid memory
    int ic = g / 7, ky = g - ic * 7;
    aoff[kb] = (ic * 69 + ky) * 144 + 4 * lo + w * 2304;
  }
  const float bias0 = cb[lo];
  const float bias1 = cb[32 + lo];
  float pool0 = 0.f, pool1 = 0.f;
  __syncthreads();

  const char* sb = (const char*)s_img;
  for (int tp = 0; tp < 4; ++tp) {     // pairs of output rows
    f32x16 a0 = {}, a1 = {}, a2 = {}, a3 = {};
#pragma unroll
    for (int kb = 0; kb < 12; ++kb) {
      const char* p = sb + aoff[kb] + tp * 576;
      union { half8 v; uint u[4]; } f0, f1;
      f0.u[0] = *(const uint*)(p);
      f0.u[1] = *(const uint*)(p + 4);
      f0.u[2] = *(const uint*)(p + 8);
      f0.u[3] = *(const uint*)(p + 12);
      f1.u[0] = *(const uint*)(p + 288);
      f1.u[1] = *(const uint*)(p + 292);
      f1.u[2] = *(const uint*)(p + 296);
      f1.u[3] = *(const uint*)(p + 300);
      a0 = __builtin_amdgcn_mfma_f32_32x32x16_f16(f0.v, bf[kb],      a0, 0, 0, 0);
      a1 = __builtin_amdgcn_mfma_f32_32x32x16_f16(f0.v, bf[12 + kb], a1, 0, 0, 0);
      a2 = __builtin_amdgcn_mfma_f32_32x32x16_f16(f1.v, bf[kb],      a2, 0, 0, 0);
      a3 = __builtin_amdgcn_mfma_f32_32x32x16_f16(f1.v, bf[12 + kb], a3, 0, 0, 0);
    }
    float s0 = 0.f, s1 = 0.f;
#pragma unroll
    for (int r = 0; r < 16; ++r) {
      s0 += fmaxf(a0[r] + bias0, 0.f) + fmaxf(a2[r] + bias0, 0.f);
      s1 += fmaxf(a1[r] + bias1, 0.f) + fmaxf(a3[r] + bias1, 0.f);
    }
    pool0 += s0;
    pool1 += s1;
  }
  pool0 += __shfl_xor(pool0, 32);
  pool1 += __shfl_xor(pool1, 32);
  if (lane < 32) {
    atomicAdd(&s_pool[lo], pool0);
    atomicAdd(&s_pool[32 + lo], pool1);
  }
  __syncthreads();
  if (tid < 64) enc[n * 64 + tid] = s_pool[tid] * (1.f / 1024.f);
}

// ---------- proj: relu(enc @ pw + pb) -> h16 [2048][512] fp16 ----------
__global__ __launch_bounds__(256) void proj_kernel(
    const float* __restrict__ enc, const float* __restrict__ pw,
    const float* __restrict__ pb, ushort* __restrict__ h16) {
  int c = ((blockIdx.x & 1) << 8) | threadIdx.x;
  int r0 = (blockIdx.x >> 1) << 3;
  float bias = pb[c];
  float acc[8];
#pragma unroll
  for (int r = 0; r < 8; ++r) acc[r] = bias;
#pragma unroll 4
  for (int k = 0; k < 64; ++k) {
    float w = pw[k * 512 + c];
#pragma unroll
    for (int r = 0; r < 8; ++r) acc[r] = fmaf(enc[(r0 + r) * 64 + k], w, acc[r]);
  }
#pragma unroll
  for (int r = 0; r < 8; ++r)
    h16[(r0 + r) * 512 + c] = __builtin_bit_cast(ushort, (_Float16)fmaxf(acc[r], 0.f));
}

// ---------- radius-KNN: one block per node; den stores 1/count ----------
__global__ __launch_bounds__(256) void knn_kernel(
    const float* __restrict__ pos, int* __restrict__ nbr, float* __restrict__ den) {
  __shared__ float s_d2[NNODES];
  __shared__ int s_idx[NNODES];
  __shared__ int s_cnt;
  const int i = blockIdx.x;
  const int tid = threadIdx.x;
  if (tid == 0) s_cnt = 0;
  __syncthreads();
  const float px = pos[2 * i] * 32.f, py = pos[2 * i + 1] * 32.f;
#pragma unroll
  for (int r = 0; r < 8; ++r) {
    int j = tid + (r << 8);
    float2 q = ((const float2*)pos)[j];
    float dx = q.x * 32.f - px, dy = q.y * 32.f - py;
    float d2 = dx * dx + dy * dy;
    if (d2 <= 2.0f && j != i) {
      int slot = atomicAdd(&s_cnt, 1);
      s_d2[slot] = d2;
      s_idx[slot] = j;
    }
  }
  __syncthreads();
  if (tid < 64) {
    const int lane = tid;
    const int cnt = s_cnt;
    int nf = 0;
#pragma unroll
    for (int k = 0; k < 5; ++k) {
      float best = 1e30f;
      int bslot = 0x7fffffff;
      for (int e = lane; e < cnt; e += 64) {
        float d = s_d2[e];
        if (d < best) { best = d; bslot = e; }
      }
#pragma unroll
      for (int off = 1; off < 64; off <<= 1) {
        float od = __shfl_xor(best, off);
        int os = __shfl_xor(bslot, off);
        if (od < best || (od == best && os < bslot)) { best = od; bslot = os; }
      }
      bool got = (best < 1e30f);
      if (lane == 0) nbr[i * 5 + k] = got ? s_idx[bslot] : -1;
      if (got) { s_d2[bslot] = 1e30f; ++nf; }
    }
    if (lane == 0) den[i] = 1.f / (float)(nf > 0 ? nf : 1);
  }
}

// ---------- agg16[i][d] = mean of valid h16[nbr][d] ----------
__global__ __launch_bounds__(256) void agg_kernel(
    const ushort* __restrict__ h16, const int* __restrict__ nbr,
    const float* __restrict__ den, ushort* __restrict__ agg16) {
  int i = blockIdx.x >> 1;
  int d = ((blockIdx.x & 1) << 8) + threadIdx.x;
  const _Float16* hp = (const _Float16*)h16;
  float s = 0.f;
#pragma unroll
  for (int k = 0; k < 5; ++k) {
    int j = nbr[i * 5 + k];
    if (j >= 0) s += (float)hp[j * 512 + d];
  }
  agg16[i * 512 + d] = __builtin_bit_cast(ushort, (_Float16)(s * den[i]));
}

// ---------- GNN layer: out = relu(h@Ws + agg@Wn + b), fused dual fp16 MFMA ----------
// 256 blocks (32 bm x 8 bn), 64x64 tile, BK=64 over K=512 (8 iters), glds dbuf.
// Buffer layout (ushort idx): Ah [0,4096) Ag [4096,8192) Bs [8192,12288) Bn [12288,16384).
__global__ __launch_bounds__(256) void gnn_gemm_kernel(
    const ushort* __restrict__ hA, const ushort* __restrict__ agg,
    const ushort* __restrict__ Ws, const ushort* __restrict__ Wn,
    const float* __restrict__ bias, ushort* __restrict__ hout,
    float* __restrict__ fout, int final_layer) {
  __shared__ ushort s_lds[2][16384];
  const int tid = threadIdx.x;
  const int lane = tid & 63;
  const int hi = lane >> 5, lo = lane & 31;
  const int wu = __builtin_amdgcn_readfirstlane(tid >> 6);
  const int wr = wu >> 1, wc = wu & 1;
  const int bm = blockIdx.x >> 3, bn = blockIdx.x & 7;
  const int r0 = bm << 6, c0 = bn << 6;

  auto STAGE = [&](int buf, int it) {
    int k0 = it << 6;
    const ushort* ph = hA  + (r0 + lane) * 512 + k0 + 8 * wu;
    const ushort* pg = agg + (r0 + lane) * 512 + k0 + 8 * wu;
    const ushort* ps = Ws  + (c0 + lane) * 512 + k0 + 8 * wu;
    const ushort* pn = Wn  + (c0 + lane) * 512 + k0 + 8 * wu;
    ushort* lb = &s_lds[buf][wu << 9];
#define GLDS(SRC, DST) __builtin_amdgcn_global_load_lds( \
      (const __attribute__((address_space(1))) void*)(SRC), \
      (__attribute__((address_space(3))) void*)(DST), 16, 0, 0)
    GLDS(ph, lb);            GLDS(ph + 32, lb + 2048);
    GLDS(pg, lb + 4096);     GLDS(pg + 32, lb + 6144);
    GLDS(ps, lb + 8192);     GLDS(ps + 32, lb + 10240);
    GLDS(pn, lb + 12288);    GLDS(pn + 32, lb + 14336);
#undef GLDS
  };

  f32x16 accS = {}, accN = {};
  STAGE(0, 0);
  __syncthreads();
  int cur = 0;
  for (int it = 0; it < 8; ++it) {
    if (it < 7) STAGE(cur ^ 1, it + 1);
    const half8* pAh = (const half8*)&s_lds[cur][0];
    const half8* pAg = (const half8*)&s_lds[cur][4096];
    const half8* pBs = (const half8*)&s_lds[cur][8192];
    const half8* pBn = (const half8*)&s_lds[cur][12288];
#pragma unroll
    for (int ks = 0; ks < 4; ++ks) {
      int gi = (2 * ks + hi) * 64;
      half8 ah = pAh[gi + 32 * wr + lo];
      half8 bs = pBs[gi + 32 * wc + lo];
      accS = __builtin_amdgcn_mfma_f32_32x32x16_f16(ah, bs, accS, 0, 0, 0);
      half8 ag = pAg[gi + 32 * wr + lo];
      half8 bn2 = pBn[gi + 32 * wc + lo];
      accN = __builtin_amdgcn_mfma_f32_32x32x16_f16(ag, bn2, accN, 0, 0, 0);
    }
    __syncthreads();
    cur ^= 1;
  }

  const int col = c0 + 32 * wc + lo;
  const float b = bias[col];
#pragma unroll
  for (int r = 0; r < 16; ++r) {
    int row = r0 + 32 * wr + (r & 3) + ((r >> 2) << 3) + (hi << 2);
    float v = fmaxf(accS[r] + accN[r] + b, 0.f);
    if (final_layer) fout[row * 512 + col] = v;
    else hout[row * 512 + col] = __builtin_bit_cast(ushort, (_Float16)v);
  }
}

extern "C" void kernel_launch(void* const* d_in, const int* in_sizes, int n_in,
                              void* d_out, int out_size, void* d_ws, size_t ws_size,
                              hipStream_t stream) {
  const float* imgs   = (const float*)d_in[0];
  const float* pos    = (const float*)d_in[1];
  const float* conv_w = (const float*)d_in[2];
  const float* conv_b = (const float*)d_in[3];
  const float* proj_w = (const float*)d_in[4];
  const float* proj_b = (const float*)d_in[5];
  const float* w_self = (const float*)d_in[6];
  const float* w_nbr  = (const float*)d_in[7];
  const float* b_gnn  = (const float*)d_in[8];

  char* ws = (char*)d_ws;
  ushort* wfrag = (ushort*)(ws);
  float*  enc   = (float*) (ws + 32768);
  ushort* h16a  = (ushort*)(ws + 557056);
  ushort* h16b  = (ushort*)(ws + 2654208);
  ushort* agg16 = (ushort*)(ws + 4751360);
  ushort* wT16  = (ushort*)(ws + 6848512);
  int*    nbr   = (int*)   (ws + 11042816);
  float*  den   = (float*) (ws + 11083776);

  prep_wfrag_kernel<<<48, 256, 0, stream>>>(conv_w, wfrag);
  prep_wT_kernel<<<512, 256, 0, stream>>>(w_self, w_nbr, wT16);
  knn_kernel<<<NNODES, 256, 0, stream>>>(pos, nbr, den);
  conv_pool_kernel<<<NNODES, 256, 0, stream>>>(imgs, wfrag, conv_b, enc);
  proj_kernel<<<512, 256, 0, stream>>>(enc, proj_w, proj_b, h16a);

  for (int l = 0; l < 4; ++l) {
    ushort* hin  = (l & 1) ? h16b : h16a;
    ushort* hnew = (l & 1) ? h16a : h16b;
    agg_kernel<<<4096, 256, 0, stream>>>(hin, nbr, den, agg16);
    gnn_gemm_kernel<<<256, 256, 0, stream>>>(
        hin, agg16, wT16 + l * 262144, wT16 + (4 + l) * 262144,
        b_gnn + l * 512, hnew, (float*)d_out, (l == 3) ? 1 : 0);
  }
}